// Round 2
// baseline (2075.788 us; speedup 1.0000x reference)
//
#include <hip/hip_runtime.h>

typedef __bf16 bf16x8 __attribute__((ext_vector_type(8)));
typedef float f32x4 __attribute__((ext_vector_type(4)));
using gptr_t = const __attribute__((address_space(1))) void*;
using sptr_t = __attribute__((address_space(3))) void*;

#define B_ 2
#define S_ 2048
#define D_ 4096
#define H_ 32
#define KV_ 8
#define G_ 4
#define HD_ 128
#define P_ 1024
#define T_ 3072

__device__ inline bf16x8 cvt8(const float4 a, const float4 b) {
  bf16x8 r;
  r[0] = (__bf16)a.x; r[1] = (__bf16)a.y; r[2] = (__bf16)a.z; r[3] = (__bf16)a.w;
  r[4] = (__bf16)b.x; r[5] = (__bf16)b.y; r[6] = (__bf16)b.z; r[7] = (__bf16)b.w;
  return r;
}

// ---------------- f32 -> bf16 elementwise convert (8 elems/thread) ----------
__global__ __launch_bounds__(256) void cvt_f32_bf16(const float* __restrict__ in,
                                                    __bf16* __restrict__ out) {
  const long i = ((long)blockIdx.x * 256 + threadIdx.x) * 8;
  float4 a = *(const float4*)(in + i);
  float4 b = *(const float4*)(in + i + 4);
  *(bf16x8*)(out + i) = cvt8(a, b);
}

// ------------- transpose: out[c][r] = bf16(in[r][c]), in f32 R x C ----------
__global__ __launch_bounds__(256) void transpose2d(const float* __restrict__ in,
                                                   __bf16* __restrict__ out,
                                                   int R, int C) {
  __shared__ float tl[32][33];
  const int tx = threadIdx.x, ty = threadIdx.y;
  const int c0 = blockIdx.x * 32, r0 = blockIdx.y * 32;
#pragma unroll
  for (int i = 0; i < 4; ++i)
    tl[ty + i * 8][tx] = in[(long)(r0 + ty + i * 8) * C + c0 + tx];
  __syncthreads();
#pragma unroll
  for (int i = 0; i < 4; ++i)
    out[(long)(c0 + ty + i * 8) * R + r0 + tx] = (__bf16)tl[tx][ty + i * 8];
}

// ------- build concat bf16 K cache: kc[b][kvh][j][hd], j in [0,T) -----------
__global__ __launch_bounds__(256) void build_kc(const float* __restrict__ pk,
                                                const __bf16* __restrict__ kv,
                                                __bf16* __restrict__ kc) {
  const int i = blockIdx.x * 256 + threadIdx.x;
  const int hd0 = (i & 15) * 8;
  const int row = i >> 4;                 // (b*KV+kvh)*T + j
  const int j = row % T_;
  const int bk = row / T_;
  const int b = bk >> 3, kvh = bk & 7;
  bf16x8 v;
  if (j < P_) {
    const float* src = pk + ((long)((b * P_ + j) * KV_ + kvh)) * HD_ + hd0;
    v = cvt8(*(const float4*)src, *(const float4*)(src + 4));
  } else {
    v = *(const bf16x8*)(kv + (long)(b * S_ + (j - P_)) * 2048 + kvh * HD_ + hd0);
  }
  *(bf16x8*)(kc + (long)row * HD_ + hd0) = v;
}

// ------- build transposed+concatenated V: vt[b][kvh][hd][j], j in [0,T) -----
__global__ __launch_bounds__(256) void build_vt(const float* __restrict__ past_v,
                                                const __bf16* __restrict__ kv,
                                                __bf16* __restrict__ vt) {
  __shared__ float tl[32][33];
  const int tx = threadIdx.x, ty = threadIdx.y;
  const int j0 = blockIdx.x * 32, hd0 = blockIdx.y * 32;
  const int b = blockIdx.z >> 3, kvh = blockIdx.z & 7;
#pragma unroll
  for (int i = 0; i < 4; ++i) {
    const int j = j0 + ty + i * 8;
    float val = (j < P_)
        ? past_v[((long)((b * P_ + j) * KV_ + kvh)) * HD_ + hd0 + tx]
        : (float)kv[(long)(b * S_ + (j - P_)) * 2048 + 1024 + kvh * HD_ + hd0 + tx];
    tl[ty + i * 8][tx] = val;
  }
  __syncthreads();
#pragma unroll
  for (int i = 0; i < 4; ++i)
    vt[((long)((b * KV_ + kvh) * HD_ + hd0 + ty + i * 8)) * T_ + j0 + tx] =
        (__bf16)tl[tx][ty + i * 8];
}

// ---------------- GEMM (m97 structure): C[M,N] = A[M,K] @ Bt[N,K]^T ---------
template <typename OutT>
__global__ __launch_bounds__(256, 3) void gemm_bt(const __bf16* __restrict__ A,
                                                  const __bf16* __restrict__ Bt,
                                                  OutT* __restrict__ C,
                                                  int M, int N, int K) {
  __shared__ __align__(16) __bf16 As[128][32];
  __shared__ __align__(16) __bf16 Bs[128][32];
  const int t = threadIdx.x;
  const int lane = t & 63, wave = t >> 6;
  const int wm = (wave >> 1) * 64, wn = (wave & 1) * 64;
  const int l15 = lane & 15, quad = lane >> 4;
  const long m0 = (long)blockIdx.y * 128, n0 = (long)blockIdx.x * 128;

  const int srow = wave * 32 + (lane >> 2);
  const int scol = (lane & 3) * 8;
  const __bf16* Ap = A + (m0 + srow) * K + scol;
  const __bf16* Bp = Bt + (n0 + srow) * K + scol;
  const long rstep = 16L * K;
  sptr_t ldsA0 = (sptr_t)&As[wave * 32][0];
  sptr_t ldsA1 = (sptr_t)&As[wave * 32 + 16][0];
  sptr_t ldsB0 = (sptr_t)&Bs[wave * 32][0];
  sptr_t ldsB1 = (sptr_t)&Bs[wave * 32 + 16][0];

  f32x4 acc[4][4];
#pragma unroll
  for (int i = 0; i < 4; ++i)
#pragma unroll
    for (int j = 0; j < 4; ++j)
#pragma unroll
      for (int e = 0; e < 4; ++e) acc[i][j][e] = 0.0f;

  const int nk = K >> 5;
  for (int kt = 0; kt < nk; ++kt) {
    __syncthreads();  // prior tile's frag reads done
    __builtin_amdgcn_global_load_lds((gptr_t)(Ap + kt * 32), ldsA0, 16, 0, 0);
    __builtin_amdgcn_global_load_lds((gptr_t)(Ap + rstep + kt * 32), ldsA1, 16, 0, 0);
    __builtin_amdgcn_global_load_lds((gptr_t)(Bp + kt * 32), ldsB0, 16, 0, 0);
    __builtin_amdgcn_global_load_lds((gptr_t)(Bp + rstep + kt * 32), ldsB1, 16, 0, 0);
    __syncthreads();  // vmcnt(0) drain + barrier: LDS tile ready
    bf16x8 aF[4], bF[4];
#pragma unroll
    for (int i = 0; i < 4; ++i)
      aF[i] = *(const bf16x8*)(&As[wm + i * 16 + l15][quad * 8]);
#pragma unroll
    for (int i = 0; i < 4; ++i)
      bF[i] = *(const bf16x8*)(&Bs[wn + i * 16 + l15][quad * 8]);
#pragma unroll
    for (int i = 0; i < 4; ++i)
#pragma unroll
      for (int j = 0; j < 4; ++j)
        acc[i][j] = __builtin_amdgcn_mfma_f32_16x16x32_bf16(aF[i], bF[j],
                                                            acc[i][j], 0, 0, 0);
  }

  // epilogue: C/D layout col=lane&15, row=quad*4+reg
#pragma unroll
  for (int i = 0; i < 4; ++i) {
    const long r0 = m0 + wm + i * 16 + quad * 4;
#pragma unroll
    for (int j = 0; j < 4; ++j) {
      const long col = n0 + wn + j * 16 + l15;
#pragma unroll
      for (int r = 0; r < 4; ++r)
        C[(r0 + r) * N + col] = (OutT)acc[i][j][r];
    }
  }
}

// ---------------- fused causal GQA flash attention ---------------------------
// grid (S/128, H, B), heavy s-tiles first. 256 threads; wave owns 32 q-rows.
// 64-key tiles. K/V reg-staged (cache-allocating loads) + double-buffered:
// loads for tile t+1 issue right after the tile-t-ready barrier, landing via
// swizzled ds_write_b128 at the next iteration (T14). XOR swizzle
// byte ^= ((row&7)<<4) on BOTH write and read sides. Ps stride 68 (136 B)
// so quad*4-row P-stores hit distinct bank groups (was 4-way at stride 72).
__global__ __launch_bounds__(256, 3) void attn_kernel(
    __bf16* qio,                     // [B,S,H,HD] in: Q, out: attn out (in-place)
    const __bf16* __restrict__ kc,   // [B,KV,T,HD] bf16 concat cache
    const __bf16* __restrict__ vt) { // [B,KV,HD,T]
  __shared__ __align__(16) __bf16 Ks[64 * 128];   // swizzled [key][hd]  16384 B
  __shared__ __align__(16) __bf16 Vs[128 * 64];   // swizzled [hd][key]  16384 B
  __shared__ __align__(16) __bf16 Ps[4][32][68];  // per-wave P          17408 B
  const int t = threadIdx.x;
  const int lane = t & 63, w = t >> 6;
  const int l15 = lane & 15, quad = lane >> 4;
  const int s0 = (15 - blockIdx.x) * 128;  // heavy tiles first
  const int h = blockIdx.y, b = blockIdx.z;
  const int kvh = h >> 2;  // G=4

  // Q fragments: aQ[mi][kt], A-layout m=lane&15, k=quad*8+j
  bf16x8 aQ[2][4];
#pragma unroll
  for (int mi = 0; mi < 2; ++mi) {
    const int qrow = s0 + w * 32 + mi * 16 + l15;
    const __bf16* qp = qio + ((long)((b * S_ + qrow) * H_ + h)) * HD_ + quad * 8;
#pragma unroll
    for (int kt = 0; kt < 4; ++kt) aQ[mi][kt] = *(const bf16x8*)(qp + kt * 32);
  }

  // staging geometry (per thread, 4 chunks of 16B each for K and V)
  const int krow = t >> 4;                  // K: base row 0..15 (+it*16)
  const int kcol8 = (t & 15) * 8;           // K: elem offset in row
  const int kswz = ((t & 15) * 16) ^ ((krow & 7) << 4);
  const int vrow = t >> 3;                  // V: base row (hd) 0..31 (+it*32)
  const int vcol8 = (t & 7) * 8;
  const int vswz = ((t & 7) * 16) ^ ((vrow & 7) << 4);
  const __bf16* kc_h = kc + (long)(b * KV_ + kvh) * T_ * HD_;
  const __bf16* vt_h = vt + (long)((b * KV_ + kvh) * HD_) * T_;
  char* KsW = (char*)Ks;
  char* VsW = (char*)Vs;

  f32x4 O[2][8];
#pragma unroll
  for (int mi = 0; mi < 2; ++mi)
#pragma unroll
    for (int f = 0; f < 8; ++f)
#pragma unroll
      for (int e = 0; e < 4; ++e) O[mi][f][e] = 0.0f;
  float m_r[2][4], l_r[2][4];
#pragma unroll
  for (int mi = 0; mi < 2; ++mi)
#pragma unroll
    for (int r = 0; r < 4; ++r) { m_r[mi][r] = -__builtin_inff(); l_r[mi][r] = 0.0f; }

  bf16x8 ones;
#pragma unroll
  for (int e = 0; e < 8; ++e) ones[e] = (__bf16)1.0f;

  const float C2 = 1.4426950408889634f * 0.08838834764831845f;  // log2e/sqrt(128)
  const int ntiles = (P_ + s0 + 128) / 64;
  const int wave_last_key = P_ + s0 + w * 32 + 31;   // max key this wave needs
  const int wave_min_bound = P_ + s0 + w * 32;       // min bound over wave rows

  const int sw = (l15 & 7) << 4;  // read-side swizzle (row&7 == l15&7 for K,V)
  const char* KsB = (const char*)Ks;
  const char* VsB = (const char*)Vs;

  // prologue: issue loads for tile 0
  bf16x8 kreg[4], vreg[4];
#pragma unroll
  for (int it = 0; it < 4; ++it) {
    kreg[it] = *(const bf16x8*)(kc_h + (long)(it * 16 + krow) * HD_ + kcol8);
    vreg[it] = *(const bf16x8*)(vt_h + (long)(it * 32 + vrow) * T_ + vcol8);
  }

  for (int tile = 0; tile < ntiles; ++tile) {
    const int j0 = tile * 64;
    __syncthreads();  // prior tile's LDS reads done
    // land staged regs into swizzled LDS
#pragma unroll
    for (int it = 0; it < 4; ++it) {
      *(bf16x8*)(KsW + (it * 16 + krow) * 256 + kswz) = kreg[it];
      *(bf16x8*)(VsW + (it * 32 + vrow) * 128 + vswz) = vreg[it];
    }
    __syncthreads();  // K/V tile ready

    // issue loads for next tile (in flight under this tile's compute)
    const int jn = (tile + 1 < ntiles) ? (tile + 1) * 64 : 0;
#pragma unroll
    for (int it = 0; it < 4; ++it) {
      kreg[it] = *(const bf16x8*)(kc_h + (long)(jn + it * 16 + krow) * HD_ + kcol8);
      vreg[it] = *(const bf16x8*)(vt_h + (long)(it * 32 + vrow) * T_ + jn + vcol8);
    }

    if (j0 > wave_last_key) continue;  // trailing tile not needed by this wave

    // QK^T: sc[mi][kf] = scores [32 q][64 keys]
    f32x4 sc[2][4];
#pragma unroll
    for (int mi = 0; mi < 2; ++mi)
#pragma unroll
      for (int kf = 0; kf < 4; ++kf)
#pragma unroll
        for (int e = 0; e < 4; ++e) sc[mi][kf][e] = 0.0f;
#pragma unroll
    for (int kf = 0; kf < 4; ++kf) {
#pragma unroll
      for (int kt = 0; kt < 4; ++kt) {
        bf16x8 bk = *(const bf16x8*)(
            KsB + ((((kf * 16 + l15) << 8) + kt * 64 + quad * 16) ^ sw));
        sc[0][kf] = __builtin_amdgcn_mfma_f32_16x16x32_bf16(aQ[0][kt], bk, sc[0][kf], 0, 0, 0);
        sc[1][kf] = __builtin_amdgcn_mfma_f32_16x16x32_bf16(aQ[1][kt], bk, sc[1][kf], 0, 0, 0);
      }
    }

    // online softmax (C layout: key=kf*16+(lane&15), q-row=quad*4+r)
    const bool need_mask = (j0 + 63 > wave_min_bound);  // wave-uniform branch
    float alpha[2][4];
#pragma unroll
    for (int mi = 0; mi < 2; ++mi) {
#pragma unroll
      for (int r = 0; r < 4; ++r) {
        float v0 = sc[mi][0][r], v1 = sc[mi][1][r];
        float v2 = sc[mi][2][r], v3 = sc[mi][3][r];
        if (need_mask) {
          const int bound = P_ + s0 + w * 32 + mi * 16 + quad * 4 + r;
          v0 = (j0 + l15 <= bound) ? v0 : -__builtin_inff();
          v1 = (j0 + 16 + l15 <= bound) ? v1 : -__builtin_inff();
          v2 = (j0 + 32 + l15 <= bound) ? v2 : -__builtin_inff();
          v3 = (j0 + 48 + l15 <= bound) ? v3 : -__builtin_inff();
        }
        float mt = fmaxf(fmaxf(v0, v1), fmaxf(v2, v3));
        mt = fmaxf(mt, __shfl_xor(mt, 1));
        mt = fmaxf(mt, __shfl_xor(mt, 2));
        mt = fmaxf(mt, __shfl_xor(mt, 4));
        mt = fmaxf(mt, __shfl_xor(mt, 8));
        const float mn = fmaxf(m_r[mi][r], mt);
        const float p0 = exp2f((v0 - mn) * C2);
        const float p1 = exp2f((v1 - mn) * C2);
        const float p2 = exp2f((v2 - mn) * C2);
        const float p3 = exp2f((v3 - mn) * C2);
        alpha[mi][r] = exp2f((m_r[mi][r] - mn) * C2);
        m_r[mi][r] = mn;
        const int row = mi * 16 + quad * 4 + r;
        Ps[w][row][l15] = (__bf16)p0;
        Ps[w][row][16 + l15] = (__bf16)p1;
        Ps[w][row][32 + l15] = (__bf16)p2;
        Ps[w][row][48 + l15] = (__bf16)p3;
      }
    }
    // rescale O
#pragma unroll
    for (int mi = 0; mi < 2; ++mi)
#pragma unroll
      for (int f = 0; f < 8; ++f)
#pragma unroll
        for (int r = 0; r < 4; ++r) O[mi][f][r] *= alpha[mi][r];

    // PV + row sums via MFMA (each bV feeds 2 MFMAs)
    f32x4 sums[2];
#pragma unroll
    for (int e = 0; e < 4; ++e) { sums[0][e] = 0.0f; sums[1][e] = 0.0f; }
#pragma unroll
    for (int kf2 = 0; kf2 < 2; ++kf2) {
      bf16x8 aP0 = *(const bf16x8*)(&Ps[w][l15][kf2 * 32 + quad * 8]);
      bf16x8 aP1 = *(const bf16x8*)(&Ps[w][16 + l15][kf2 * 32 + quad * 8]);
      sums[0] = __builtin_amdgcn_mfma_f32_16x16x32_bf16(aP0, ones, sums[0], 0, 0, 0);
      sums[1] = __builtin_amdgcn_mfma_f32_16x16x32_bf16(aP1, ones, sums[1], 0, 0, 0);
#pragma unroll
      for (int f = 0; f < 8; ++f) {
        bf16x8 bV = *(const bf16x8*)(
            VsB + ((((f * 16 + l15) << 7) + kf2 * 64 + quad * 16) ^ sw));
        O[0][f] = __builtin_amdgcn_mfma_f32_16x16x32_bf16(aP0, bV, O[0][f], 0, 0, 0);
        O[1][f] = __builtin_amdgcn_mfma_f32_16x16x32_bf16(aP1, bV, O[1][f], 0, 0, 0);
      }
    }
#pragma unroll
    for (int mi = 0; mi < 2; ++mi)
#pragma unroll
      for (int r = 0; r < 4; ++r)
        l_r[mi][r] = l_r[mi][r] * alpha[mi][r] + sums[mi][r];
  }

  // epilogue: normalize, store in-place
#pragma unroll
  for (int mi = 0; mi < 2; ++mi) {
#pragma unroll
    for (int r = 0; r < 4; ++r) {
      const float inv = 1.0f / l_r[mi][r];
      const long row =
          (long)((b * S_ + s0 + w * 32 + mi * 16 + quad * 4 + r) * H_ + h);
#pragma unroll
      for (int f = 0; f < 8; ++f)
        qio[row * HD_ + f * 16 + l15] = (__bf16)(O[mi][f][r] * inv);
    }
  }
}

extern "C" void kernel_launch(void* const* d_in, const int* in_sizes, int n_in,
                              void* d_out, int out_size, void* d_ws, size_t ws_size,
                              hipStream_t stream) {
  const float* x  = (const float*)d_in[0];
  const float* pk = (const float*)d_in[1];
  const float* pv = (const float*)d_in[2];
  const float* Wq = (const float*)d_in[3];
  const float* Wk = (const float*)d_in[4];
  const float* Wv = (const float*)d_in[5];
  const float* Wo = (const float*)d_in[6];
  float* out = (float*)d_out;
  char* ws = (char*)d_ws;
  // workspace layout:
  __bf16* wt  = (__bf16*)ws;                        // 32M: W^T staging
  __bf16* kvb = (__bf16*)(ws + (size_t)16777216);   // 16M: fused k/v gemm out
  __bf16* q   = (__bf16*)(ws + (size_t)33554432);   // 32M: [B,S,H,HD]
  __bf16* xb  = (__bf16*)(ws + (size_t)67108864);   // 32M: x bf16 (dead after kv gemm)
  __bf16* kc  = (__bf16*)(ws + (size_t)67108864);   // 12.6M (aliases dead xb)
  __bf16* vt  = (__bf16*)(ws + (size_t)79691776);   // 12.6M

  dim3 tb(32, 8);
  cvt_f32_bf16<<<8192, 256, 0, stream>>>(x, xb);
  // q = x @ Wq
  transpose2d<<<dim3(128, 128), tb, 0, stream>>>(Wq, wt, D_, D_);
  gemm_bt<__bf16><<<dim3(32, 32), 256, 0, stream>>>(xb, wt, q, B_ * S_, D_, D_);
  // fused [k|v] = x @ [Wk|Wv]  (N=2048, 512 blocks)
  transpose2d<<<dim3(32, 128), tb, 0, stream>>>(Wk, wt, D_, KV_ * HD_);
  transpose2d<<<dim3(32, 128), tb, 0, stream>>>(Wv, wt + (size_t)1024 * 4096, D_, KV_ * HD_);
  gemm_bt<__bf16><<<dim3(16, 32), 256, 0, stream>>>(xb, wt, kvb, B_ * S_, 2048, D_);
  // concat bf16 caches (xb dead from here; kc/vt overlay it)
  build_kc<<<3072, 256, 0, stream>>>(pk, kvb, kc);
  build_vt<<<dim3(96, 4, 16), tb, 0, stream>>>(pv, kvb, vt);
  // attention (in-place on q); heavy s-tiles dispatch first via reversed x
  attn_kernel<<<dim3(16, 32, 2), 256, 0, stream>>>(q, kc, vt);
  // out = attn @ Wo  (f32 output)
  transpose2d<<<dim3(128, 128), tb, 0, stream>>>(Wo, wt, D_, D_);
  gemm_bt<float><<<dim3(32, 32), 256, 0, stream>>>(q, wt, out, B_ * S_, D_, D_);
}

// Round 3
// 1595.973 us; speedup vs baseline: 1.3006x; 1.3006x over previous
//
#include <hip/hip_runtime.h>

typedef __bf16 bf16x8 __attribute__((ext_vector_type(8)));
typedef float f32x4 __attribute__((ext_vector_type(4)));
using gptr_t = const __attribute__((address_space(1))) void*;
using sptr_t = __attribute__((address_space(3))) void*;

#define B_ 2
#define S_ 2048
#define D_ 4096
#define H_ 32
#define KV_ 8
#define G_ 4
#define HD_ 128
#define P_ 1024
#define T_ 3072

__device__ inline bf16x8 cvt8(const float4 a, const float4 b) {
  bf16x8 r;
  r[0] = (__bf16)a.x; r[1] = (__bf16)a.y; r[2] = (__bf16)a.z; r[3] = (__bf16)a.w;
  r[4] = (__bf16)b.x; r[5] = (__bf16)b.y; r[6] = (__bf16)b.z; r[7] = (__bf16)b.w;
  return r;
}

// ---------------- f32 -> bf16 elementwise convert (8 elems/thread) ----------
__global__ __launch_bounds__(256) void cvt_f32_bf16(const float* __restrict__ in,
                                                    __bf16* __restrict__ out) {
  const long i = ((long)blockIdx.x * 256 + threadIdx.x) * 8;
  float4 a = *(const float4*)(in + i);
  float4 b = *(const float4*)(in + i + 4);
  *(bf16x8*)(out + i) = cvt8(a, b);
}

// ------------- transpose: out[c][r] = bf16(in[r][c]), in f32 R x C ----------
__global__ __launch_bounds__(256) void transpose2d(const float* __restrict__ in,
                                                   __bf16* __restrict__ out,
                                                   int R, int C) {
  __shared__ float tl[32][33];
  const int tx = threadIdx.x, ty = threadIdx.y;
  const int c0 = blockIdx.x * 32, r0 = blockIdx.y * 32;
#pragma unroll
  for (int i = 0; i < 4; ++i)
    tl[ty + i * 8][tx] = in[(long)(r0 + ty + i * 8) * C + c0 + tx];
  __syncthreads();
#pragma unroll
  for (int i = 0; i < 4; ++i)
    out[(long)(c0 + ty + i * 8) * R + r0 + tx] = (__bf16)tl[tx][ty + i * 8];
}

// ------- build concat bf16 K cache: kc[b][kvh][j][hd], j in [0,T) -----------
__global__ __launch_bounds__(256) void build_kc(const float* __restrict__ pk,
                                                const __bf16* __restrict__ kv,
                                                __bf16* __restrict__ kc) {
  const int i = blockIdx.x * 256 + threadIdx.x;
  const int hd0 = (i & 15) * 8;
  const int row = i >> 4;                 // (b*KV+kvh)*T + j
  const int j = row % T_;
  const int bk = row / T_;
  const int b = bk >> 3, kvh = bk & 7;
  bf16x8 v;
  if (j < P_) {
    const float* src = pk + ((long)((b * P_ + j) * KV_ + kvh)) * HD_ + hd0;
    v = cvt8(*(const float4*)src, *(const float4*)(src + 4));
  } else {
    v = *(const bf16x8*)(kv + (long)(b * S_ + (j - P_)) * 2048 + kvh * HD_ + hd0);
  }
  *(bf16x8*)(kc + (long)row * HD_ + hd0) = v;
}

// ------- build transposed+concatenated V: vt[b][kvh][hd][j], j in [0,T) -----
__global__ __launch_bounds__(256) void build_vt(const float* __restrict__ past_v,
                                                const __bf16* __restrict__ kv,
                                                __bf16* __restrict__ vt) {
  __shared__ float tl[32][33];
  const int tx = threadIdx.x, ty = threadIdx.y;
  const int j0 = blockIdx.x * 32, hd0 = blockIdx.y * 32;
  const int b = blockIdx.z >> 3, kvh = blockIdx.z & 7;
#pragma unroll
  for (int i = 0; i < 4; ++i) {
    const int j = j0 + ty + i * 8;
    float val = (j < P_)
        ? past_v[((long)((b * P_ + j) * KV_ + kvh)) * HD_ + hd0 + tx]
        : (float)kv[(long)(b * S_ + (j - P_)) * 2048 + 1024 + kvh * HD_ + hd0 + tx];
    tl[ty + i * 8][tx] = val;
  }
  __syncthreads();
#pragma unroll
  for (int i = 0; i < 4; ++i)
    vt[((long)((b * KV_ + kvh) * HD_ + hd0 + ty + i * 8)) * T_ + j0 + tx] =
        (__bf16)tl[tx][ty + i * 8];
}

// ---------------- GEMM (m97 structure): C[M,N] = A[M,K] @ Bt[N,K]^T ---------
template <typename OutT>
__global__ __launch_bounds__(256, 3) void gemm_bt(const __bf16* __restrict__ A,
                                                  const __bf16* __restrict__ Bt,
                                                  OutT* __restrict__ C,
                                                  int M, int N, int K) {
  __shared__ __align__(16) __bf16 As[128][32];
  __shared__ __align__(16) __bf16 Bs[128][32];
  const int t = threadIdx.x;
  const int lane = t & 63, wave = t >> 6;
  const int wm = (wave >> 1) * 64, wn = (wave & 1) * 64;
  const int l15 = lane & 15, quad = lane >> 4;
  const long m0 = (long)blockIdx.y * 128, n0 = (long)blockIdx.x * 128;

  const int srow = wave * 32 + (lane >> 2);
  const int scol = (lane & 3) * 8;
  const __bf16* Ap = A + (m0 + srow) * K + scol;
  const __bf16* Bp = Bt + (n0 + srow) * K + scol;
  const long rstep = 16L * K;
  sptr_t ldsA0 = (sptr_t)&As[wave * 32][0];
  sptr_t ldsA1 = (sptr_t)&As[wave * 32 + 16][0];
  sptr_t ldsB0 = (sptr_t)&Bs[wave * 32][0];
  sptr_t ldsB1 = (sptr_t)&Bs[wave * 32 + 16][0];

  f32x4 acc[4][4];
#pragma unroll
  for (int i = 0; i < 4; ++i)
#pragma unroll
    for (int j = 0; j < 4; ++j)
#pragma unroll
      for (int e = 0; e < 4; ++e) acc[i][j][e] = 0.0f;

  const int nk = K >> 5;
  for (int kt = 0; kt < nk; ++kt) {
    __syncthreads();  // prior tile's frag reads done
    __builtin_amdgcn_global_load_lds((gptr_t)(Ap + kt * 32), ldsA0, 16, 0, 0);
    __builtin_amdgcn_global_load_lds((gptr_t)(Ap + rstep + kt * 32), ldsA1, 16, 0, 0);
    __builtin_amdgcn_global_load_lds((gptr_t)(Bp + kt * 32), ldsB0, 16, 0, 0);
    __builtin_amdgcn_global_load_lds((gptr_t)(Bp + rstep + kt * 32), ldsB1, 16, 0, 0);
    __syncthreads();  // vmcnt(0) drain + barrier: LDS tile ready
    bf16x8 aF[4], bF[4];
#pragma unroll
    for (int i = 0; i < 4; ++i)
      aF[i] = *(const bf16x8*)(&As[wm + i * 16 + l15][quad * 8]);
#pragma unroll
    for (int i = 0; i < 4; ++i)
      bF[i] = *(const bf16x8*)(&Bs[wn + i * 16 + l15][quad * 8]);
#pragma unroll
    for (int i = 0; i < 4; ++i)
#pragma unroll
      for (int j = 0; j < 4; ++j)
        acc[i][j] = __builtin_amdgcn_mfma_f32_16x16x32_bf16(aF[i], bF[j],
                                                            acc[i][j], 0, 0, 0);
  }

  // epilogue: C/D layout col=lane&15, row=quad*4+reg
#pragma unroll
  for (int i = 0; i < 4; ++i) {
    const long r0 = m0 + wm + i * 16 + quad * 4;
#pragma unroll
    for (int j = 0; j < 4; ++j) {
      const long col = n0 + wn + j * 16 + l15;
#pragma unroll
      for (int r = 0; r < 4; ++r)
        C[(r0 + r) * N + col] = (OutT)acc[i][j][r];
    }
  }
}

// ---------------- fused causal GQA flash attention ---------------------------
// grid (S/128, H, B), heavy s-tiles first. 256 threads; wave owns 32 q-rows.
// 64-key tiles. Round-0 phase structure (proven fastest): per tile,
//   barrier; 8x16B plain cache-allocating loads -> regs; swizzled
//   ds_write_b128; barrier; compute. Register lifetimes stay inside one
//   phase (round 2's cross-barrier staging regs were spilled to scratch:
//   WRITE_SIZE 33MB -> 974MB). No global_load_lds (round 1: bypasses
//   cache allocation, FETCH 121MB -> 1.18GB on 45x-re-read KV).
// XOR swizzle byte ^= ((row&7)<<4) on write and read. Ps stride 68.
__global__ __launch_bounds__(256, 3) void attn_kernel(
    __bf16* qio,                     // [B,S,H,HD] in: Q, out: attn out (in-place)
    const __bf16* __restrict__ kc,   // [B,KV,T,HD] bf16 concat cache
    const __bf16* __restrict__ vt) { // [B,KV,HD,T]
  __shared__ __align__(16) __bf16 Ks[64 * 128];   // swizzled [key][hd]  16384 B
  __shared__ __align__(16) __bf16 Vs[128 * 64];   // swizzled [hd][key]  16384 B
  __shared__ __align__(16) __bf16 Ps[4][32][68];  // per-wave P          17408 B
  const int t = threadIdx.x;
  const int lane = t & 63, w = t >> 6;
  const int l15 = lane & 15, quad = lane >> 4;
  const int s0 = (15 - blockIdx.x) * 128;  // heavy tiles first
  const int h = blockIdx.y, b = blockIdx.z;
  const int kvh = h >> 2;  // G=4

  // Q fragments: aQ[mi][kt], A-layout m=lane&15, k=quad*8+j
  bf16x8 aQ[2][4];
#pragma unroll
  for (int mi = 0; mi < 2; ++mi) {
    const int qrow = s0 + w * 32 + mi * 16 + l15;
    const __bf16* qp = qio + ((long)((b * S_ + qrow) * H_ + h)) * HD_ + quad * 8;
#pragma unroll
    for (int kt = 0; kt < 4; ++kt) aQ[mi][kt] = *(const bf16x8*)(qp + kt * 32);
  }

  // staging geometry (per thread, 4 chunks of 16B each for K and V)
  const int krow = t >> 4;                  // K: base row 0..15 (+it*16)
  const int kcol8 = (t & 15) * 8;           // K: elem offset in row
  const int kswz = ((t & 15) * 16) ^ ((krow & 7) << 4);
  const int vrow = t >> 3;                  // V: base row (hd) 0..31 (+it*32)
  const int vcol8 = (t & 7) * 8;
  const int vswz = ((t & 7) * 16) ^ ((vrow & 7) << 4);
  const __bf16* kc_h = kc + (long)(b * KV_ + kvh) * T_ * HD_;
  const __bf16* vt_h = vt + (long)((b * KV_ + kvh) * HD_) * T_;
  char* KsW = (char*)Ks;
  char* VsW = (char*)Vs;

  f32x4 O[2][8];
#pragma unroll
  for (int mi = 0; mi < 2; ++mi)
#pragma unroll
    for (int f = 0; f < 8; ++f)
#pragma unroll
      for (int e = 0; e < 4; ++e) O[mi][f][e] = 0.0f;
  float m_r[2][4], l_r[2][4];
#pragma unroll
  for (int mi = 0; mi < 2; ++mi)
#pragma unroll
    for (int r = 0; r < 4; ++r) { m_r[mi][r] = -__builtin_inff(); l_r[mi][r] = 0.0f; }

  bf16x8 ones;
#pragma unroll
  for (int e = 0; e < 8; ++e) ones[e] = (__bf16)1.0f;

  const float C2 = 1.4426950408889634f * 0.08838834764831845f;  // log2e/sqrt(128)
  const int ntiles = (P_ + s0 + 128) / 64;
  const int wave_last_key = P_ + s0 + w * 32 + 31;   // max key this wave needs
  const int wave_min_bound = P_ + s0 + w * 32;       // min bound over wave rows

  const int sw = (l15 & 7) << 4;  // read-side swizzle (row&7 == l15&7 for K,V)
  const char* KsB = (const char*)Ks;
  const char* VsB = (const char*)Vs;

  for (int tile = 0; tile < ntiles; ++tile) {
    const int j0 = tile * 64;
    __syncthreads();  // prior tile's LDS reads done
    {
      // load this tile (8 outstanding 16B loads), then land into swizzled LDS
      bf16x8 kreg[4], vreg[4];
#pragma unroll
      for (int it = 0; it < 4; ++it) {
        kreg[it] = *(const bf16x8*)(kc_h + (long)(j0 + it * 16 + krow) * HD_ + kcol8);
        vreg[it] = *(const bf16x8*)(vt_h + (long)(it * 32 + vrow) * T_ + j0 + vcol8);
      }
#pragma unroll
      for (int it = 0; it < 4; ++it) {
        *(bf16x8*)(KsW + (it * 16 + krow) * 256 + kswz) = kreg[it];
        *(bf16x8*)(VsW + (it * 32 + vrow) * 128 + vswz) = vreg[it];
      }
    }
    __syncthreads();  // K/V tile ready

    if (j0 > wave_last_key) continue;  // trailing tile not needed by this wave

    // QK^T: sc[mi][kf] = scores [32 q][64 keys]
    f32x4 sc[2][4];
#pragma unroll
    for (int mi = 0; mi < 2; ++mi)
#pragma unroll
      for (int kf = 0; kf < 4; ++kf)
#pragma unroll
        for (int e = 0; e < 4; ++e) sc[mi][kf][e] = 0.0f;
#pragma unroll
    for (int kf = 0; kf < 4; ++kf) {
#pragma unroll
      for (int kt = 0; kt < 4; ++kt) {
        bf16x8 bk = *(const bf16x8*)(
            KsB + ((((kf * 16 + l15) << 8) + kt * 64 + quad * 16) ^ sw));
        sc[0][kf] = __builtin_amdgcn_mfma_f32_16x16x32_bf16(aQ[0][kt], bk, sc[0][kf], 0, 0, 0);
        sc[1][kf] = __builtin_amdgcn_mfma_f32_16x16x32_bf16(aQ[1][kt], bk, sc[1][kf], 0, 0, 0);
      }
    }

    // online softmax (C layout: key=kf*16+(lane&15), q-row=quad*4+r)
    const bool need_mask = (j0 + 63 > wave_min_bound);  // wave-uniform branch
    float alpha[2][4];
#pragma unroll
    for (int mi = 0; mi < 2; ++mi) {
#pragma unroll
      for (int r = 0; r < 4; ++r) {
        float v0 = sc[mi][0][r], v1 = sc[mi][1][r];
        float v2 = sc[mi][2][r], v3 = sc[mi][3][r];
        if (need_mask) {
          const int bound = P_ + s0 + w * 32 + mi * 16 + quad * 4 + r;
          v0 = (j0 + l15 <= bound) ? v0 : -__builtin_inff();
          v1 = (j0 + 16 + l15 <= bound) ? v1 : -__builtin_inff();
          v2 = (j0 + 32 + l15 <= bound) ? v2 : -__builtin_inff();
          v3 = (j0 + 48 + l15 <= bound) ? v3 : -__builtin_inff();
        }
        float mt = fmaxf(fmaxf(v0, v1), fmaxf(v2, v3));
        mt = fmaxf(mt, __shfl_xor(mt, 1));
        mt = fmaxf(mt, __shfl_xor(mt, 2));
        mt = fmaxf(mt, __shfl_xor(mt, 4));
        mt = fmaxf(mt, __shfl_xor(mt, 8));
        const float mn = fmaxf(m_r[mi][r], mt);
        const float p0 = exp2f((v0 - mn) * C2);
        const float p1 = exp2f((v1 - mn) * C2);
        const float p2 = exp2f((v2 - mn) * C2);
        const float p3 = exp2f((v3 - mn) * C2);
        alpha[mi][r] = exp2f((m_r[mi][r] - mn) * C2);
        m_r[mi][r] = mn;
        const int row = mi * 16 + quad * 4 + r;
        Ps[w][row][l15] = (__bf16)p0;
        Ps[w][row][16 + l15] = (__bf16)p1;
        Ps[w][row][32 + l15] = (__bf16)p2;
        Ps[w][row][48 + l15] = (__bf16)p3;
      }
    }
    // rescale O
#pragma unroll
    for (int mi = 0; mi < 2; ++mi)
#pragma unroll
      for (int f = 0; f < 8; ++f)
#pragma unroll
        for (int r = 0; r < 4; ++r) O[mi][f][r] *= alpha[mi][r];

    // PV + row sums via MFMA (each bV feeds 2 MFMAs)
    f32x4 sums[2];
#pragma unroll
    for (int e = 0; e < 4; ++e) { sums[0][e] = 0.0f; sums[1][e] = 0.0f; }
#pragma unroll
    for (int kf2 = 0; kf2 < 2; ++kf2) {
      bf16x8 aP0 = *(const bf16x8*)(&Ps[w][l15][kf2 * 32 + quad * 8]);
      bf16x8 aP1 = *(const bf16x8*)(&Ps[w][16 + l15][kf2 * 32 + quad * 8]);
      sums[0] = __builtin_amdgcn_mfma_f32_16x16x32_bf16(aP0, ones, sums[0], 0, 0, 0);
      sums[1] = __builtin_amdgcn_mfma_f32_16x16x32_bf16(aP1, ones, sums[1], 0, 0, 0);
#pragma unroll
      for (int f = 0; f < 8; ++f) {
        bf16x8 bV = *(const bf16x8*)(
            VsB + ((((f * 16 + l15) << 7) + kf2 * 64 + quad * 16) ^ sw));
        O[0][f] = __builtin_amdgcn_mfma_f32_16x16x32_bf16(aP0, bV, O[0][f], 0, 0, 0);
        O[1][f] = __builtin_amdgcn_mfma_f32_16x16x32_bf16(aP1, bV, O[1][f], 0, 0, 0);
      }
    }
#pragma unroll
    for (int mi = 0; mi < 2; ++mi)
#pragma unroll
      for (int r = 0; r < 4; ++r)
        l_r[mi][r] = l_r[mi][r] * alpha[mi][r] + sums[mi][r];
  }

  // epilogue: normalize, store in-place
#pragma unroll
  for (int mi = 0; mi < 2; ++mi) {
#pragma unroll
    for (int r = 0; r < 4; ++r) {
      const float inv = 1.0f / l_r[mi][r];
      const long row =
          (long)((b * S_ + s0 + w * 32 + mi * 16 + quad * 4 + r) * H_ + h);
#pragma unroll
      for (int f = 0; f < 8; ++f)
        qio[row * HD_ + f * 16 + l15] = (__bf16)(O[mi][f][r] * inv);
    }
  }
}

extern "C" void kernel_launch(void* const* d_in, const int* in_sizes, int n_in,
                              void* d_out, int out_size, void* d_ws, size_t ws_size,
                              hipStream_t stream) {
  const float* x  = (const float*)d_in[0];
  const float* pk = (const float*)d_in[1];
  const float* pv = (const float*)d_in[2];
  const float* Wq = (const float*)d_in[3];
  const float* Wk = (const float*)d_in[4];
  const float* Wv = (const float*)d_in[5];
  const float* Wo = (const float*)d_in[6];
  float* out = (float*)d_out;
  char* ws = (char*)d_ws;
  // workspace layout:
  __bf16* wt  = (__bf16*)ws;                        // 32M: W^T staging
  __bf16* kvb = (__bf16*)(ws + (size_t)16777216);   // 16M: fused k/v gemm out
  __bf16* q   = (__bf16*)(ws + (size_t)33554432);   // 32M: [B,S,H,HD]
  __bf16* xb  = (__bf16*)(ws + (size_t)67108864);   // 32M: x bf16 (dead after kv gemm)
  __bf16* kc  = (__bf16*)(ws + (size_t)67108864);   // 12.6M (aliases dead xb)
  __bf16* vt  = (__bf16*)(ws + (size_t)79691776);   // 12.6M

  dim3 tb(32, 8);
  cvt_f32_bf16<<<8192, 256, 0, stream>>>(x, xb);
  // q = x @ Wq
  transpose2d<<<dim3(128, 128), tb, 0, stream>>>(Wq, wt, D_, D_);
  gemm_bt<__bf16><<<dim3(32, 32), 256, 0, stream>>>(xb, wt, q, B_ * S_, D_, D_);
  // fused [k|v] = x @ [Wk|Wv]  (N=2048, 512 blocks)
  transpose2d<<<dim3(32, 128), tb, 0, stream>>>(Wk, wt, D_, KV_ * HD_);
  transpose2d<<<dim3(32, 128), tb, 0, stream>>>(Wv, wt + (size_t)1024 * 4096, D_, KV_ * HD_);
  gemm_bt<__bf16><<<dim3(16, 32), 256, 0, stream>>>(xb, wt, kvb, B_ * S_, 2048, D_);
  // concat bf16 caches (xb dead from here; kc/vt overlay it)
  build_kc<<<3072, 256, 0, stream>>>(pk, kvb, kc);
  build_vt<<<dim3(96, 4, 16), tb, 0, stream>>>(pv, kvb, vt);
  // attention (in-place on q); heavy s-tiles dispatch first via reversed x
  attn_kernel<<<dim3(16, 32, 2), 256, 0, stream>>>(q, kc, vt);
  // out = attn @ Wo  (f32 output)
  transpose2d<<<dim3(128, 128), tb, 0, stream>>>(Wo, wt, D_, D_);
  gemm_bt<float><<<dim3(32, 32), 256, 0, stream>>>(q, wt, out, B_ * S_, D_, D_);
}

// Round 4
// 1071.298 us; speedup vs baseline: 1.9376x; 1.4898x over previous
//
#include <hip/hip_runtime.h>

typedef __bf16 bf16x8 __attribute__((ext_vector_type(8)));
typedef float f32x4 __attribute__((ext_vector_type(4)));
using gptr_t = const __attribute__((address_space(1))) void*;
using sptr_t = __attribute__((address_space(3))) void*;

#define B_ 2
#define S_ 2048
#define D_ 4096
#define H_ 32
#define KV_ 8
#define G_ 4
#define HD_ 128
#define P_ 1024
#define T_ 3072

__device__ inline bf16x8 cvt8(const float4 a, const float4 b) {
  bf16x8 r;
  r[0] = (__bf16)a.x; r[1] = (__bf16)a.y; r[2] = (__bf16)a.z; r[3] = (__bf16)a.w;
  r[4] = (__bf16)b.x; r[5] = (__bf16)b.y; r[6] = (__bf16)b.z; r[7] = (__bf16)b.w;
  return r;
}

// ---------------- f32 -> bf16 elementwise convert (8 elems/thread) ----------
__global__ __launch_bounds__(256) void cvt_f32_bf16(const float* __restrict__ in,
                                                    __bf16* __restrict__ out) {
  const long i = ((long)blockIdx.x * 256 + threadIdx.x) * 8;
  float4 a = *(const float4*)(in + i);
  float4 b = *(const float4*)(in + i + 4);
  *(bf16x8*)(out + i) = cvt8(a, b);
}

// ------------- transpose: out[c][r] = bf16(in[r][c]), in f32 R x C ----------
__global__ __launch_bounds__(256) void transpose2d(const float* __restrict__ in,
                                                   __bf16* __restrict__ out,
                                                   int R, int C) {
  __shared__ float tl[32][33];
  const int tx = threadIdx.x, ty = threadIdx.y;
  const int c0 = blockIdx.x * 32, r0 = blockIdx.y * 32;
#pragma unroll
  for (int i = 0; i < 4; ++i)
    tl[ty + i * 8][tx] = in[(long)(r0 + ty + i * 8) * C + c0 + tx];
  __syncthreads();
#pragma unroll
  for (int i = 0; i < 4; ++i)
    out[(long)(c0 + ty + i * 8) * R + r0 + tx] = (__bf16)tl[tx][ty + i * 8];
}

// ------- build concat bf16 K cache: kc[b][kvh][j][hd], j in [0,T) -----------
__global__ __launch_bounds__(256) void build_kc(const float* __restrict__ pk,
                                                const __bf16* __restrict__ kv,
                                                __bf16* __restrict__ kc) {
  const int i = blockIdx.x * 256 + threadIdx.x;
  const int hd0 = (i & 15) * 8;
  const int row = i >> 4;                 // (b*KV+kvh)*T + j
  const int j = row % T_;
  const int bk = row / T_;
  const int b = bk >> 3, kvh = bk & 7;
  bf16x8 v;
  if (j < P_) {
    const float* src = pk + ((long)((b * P_ + j) * KV_ + kvh)) * HD_ + hd0;
    v = cvt8(*(const float4*)src, *(const float4*)(src + 4));
  } else {
    v = *(const bf16x8*)(kv + (long)(b * S_ + (j - P_)) * 2048 + kvh * HD_ + hd0);
  }
  *(bf16x8*)(kc + (long)row * HD_ + hd0) = v;
}

// ------- build transposed+concatenated V: vt[b][kvh][hd][j], j in [0,T) -----
__global__ __launch_bounds__(256) void build_vt(const float* __restrict__ past_v,
                                                const __bf16* __restrict__ kv,
                                                __bf16* __restrict__ vt) {
  __shared__ float tl[32][33];
  const int tx = threadIdx.x, ty = threadIdx.y;
  const int j0 = blockIdx.x * 32, hd0 = blockIdx.y * 32;
  const int b = blockIdx.z >> 3, kvh = blockIdx.z & 7;
#pragma unroll
  for (int i = 0; i < 4; ++i) {
    const int j = j0 + ty + i * 8;
    float val = (j < P_)
        ? past_v[((long)((b * P_ + j) * KV_ + kvh)) * HD_ + hd0 + tx]
        : (float)kv[(long)(b * S_ + (j - P_)) * 2048 + 1024 + kvh * HD_ + hd0 + tx];
    tl[ty + i * 8][tx] = val;
  }
  __syncthreads();
#pragma unroll
  for (int i = 0; i < 4; ++i)
    vt[((long)((b * KV_ + kvh) * HD_ + hd0 + ty + i * 8)) * T_ + j0 + tx] =
        (__bf16)tl[tx][ty + i * 8];
}

// ---------------- GEMM (m97 structure): C[M,N] = A[M,K] @ Bt[N,K]^T ---------
template <typename OutT>
__global__ __launch_bounds__(256, 3) void gemm_bt(const __bf16* __restrict__ A,
                                                  const __bf16* __restrict__ Bt,
                                                  OutT* __restrict__ C,
                                                  int M, int N, int K) {
  __shared__ __align__(16) __bf16 As[128][32];
  __shared__ __align__(16) __bf16 Bs[128][32];
  const int t = threadIdx.x;
  const int lane = t & 63, wave = t >> 6;
  const int wm = (wave >> 1) * 64, wn = (wave & 1) * 64;
  const int l15 = lane & 15, quad = lane >> 4;
  const long m0 = (long)blockIdx.y * 128, n0 = (long)blockIdx.x * 128;

  const int srow = wave * 32 + (lane >> 2);
  const int scol = (lane & 3) * 8;
  const __bf16* Ap = A + (m0 + srow) * K + scol;
  const __bf16* Bp = Bt + (n0 + srow) * K + scol;
  const long rstep = 16L * K;
  sptr_t ldsA0 = (sptr_t)&As[wave * 32][0];
  sptr_t ldsA1 = (sptr_t)&As[wave * 32 + 16][0];
  sptr_t ldsB0 = (sptr_t)&Bs[wave * 32][0];
  sptr_t ldsB1 = (sptr_t)&Bs[wave * 32 + 16][0];

  f32x4 acc[4][4];
#pragma unroll
  for (int i = 0; i < 4; ++i)
#pragma unroll
    for (int j = 0; j < 4; ++j)
#pragma unroll
      for (int e = 0; e < 4; ++e) acc[i][j][e] = 0.0f;

  const int nk = K >> 5;
  for (int kt = 0; kt < nk; ++kt) {
    __syncthreads();  // prior tile's frag reads done
    __builtin_amdgcn_global_load_lds((gptr_t)(Ap + kt * 32), ldsA0, 16, 0, 0);
    __builtin_amdgcn_global_load_lds((gptr_t)(Ap + rstep + kt * 32), ldsA1, 16, 0, 0);
    __builtin_amdgcn_global_load_lds((gptr_t)(Bp + kt * 32), ldsB0, 16, 0, 0);
    __builtin_amdgcn_global_load_lds((gptr_t)(Bp + rstep + kt * 32), ldsB1, 16, 0, 0);
    __syncthreads();  // vmcnt(0) drain + barrier: LDS tile ready
    bf16x8 aF[4], bF[4];
#pragma unroll
    for (int i = 0; i < 4; ++i)
      aF[i] = *(const bf16x8*)(&As[wm + i * 16 + l15][quad * 8]);
#pragma unroll
    for (int i = 0; i < 4; ++i)
      bF[i] = *(const bf16x8*)(&Bs[wn + i * 16 + l15][quad * 8]);
#pragma unroll
    for (int i = 0; i < 4; ++i)
#pragma unroll
      for (int j = 0; j < 4; ++j)
        acc[i][j] = __builtin_amdgcn_mfma_f32_16x16x32_bf16(aF[i], bF[j],
                                                            acc[i][j], 0, 0, 0);
  }

  // epilogue: C/D layout col=lane&15, row=quad*4+reg
#pragma unroll
  for (int i = 0; i < 4; ++i) {
    const long r0 = m0 + wm + i * 16 + quad * 4;
#pragma unroll
    for (int j = 0; j < 4; ++j) {
      const long col = n0 + wn + j * 16 + l15;
#pragma unroll
      for (int r = 0; r < 4; ++r)
        C[(r0 + r) * N + col] = (OutT)acc[i][j][r];
    }
  }
}

// ---------------- fused causal GQA flash attention ---------------------------
// grid (S/128, H, B), heavy s-tiles first. 256 threads; wave owns 32 q-rows.
// 64-key tiles. Round-0 phase structure + round-0 register budget:
// __launch_bounds__(256, 2) — the (256,3) bound of rounds 1-3 capped the
// unified VGPR/AGPR budget at ~168/lane, forcing the compiler to spill the
// O/aQ/sc register state to scratch every tile (VGPR_Count 84, +157..267 MB
// WRITE_SIZE). Per tile: barrier; 8x16B plain cache-allocating loads -> regs
// (phase-local lifetimes); swizzled ds_write_b128; barrier; compute.
// No global_load_lds (bypasses cache allocation; 45x-re-read KV needs L2/LLC:
// round 1 FETCH 121MB -> 1.18GB). XOR swizzle byte ^= ((row&7)<<4) on write
// and read sides. Ps stride 68 (quad*4-row P-stores conflict-free).
__global__ __launch_bounds__(256, 2) void attn_kernel(
    __bf16* qio,                     // [B,S,H,HD] in: Q, out: attn out (in-place)
    const __bf16* __restrict__ kc,   // [B,KV,T,HD] bf16 concat cache
    const __bf16* __restrict__ vt) { // [B,KV,HD,T]
  __shared__ __align__(16) __bf16 Ks[64 * 128];   // swizzled [key][hd]  16384 B
  __shared__ __align__(16) __bf16 Vs[128 * 64];   // swizzled [hd][key]  16384 B
  __shared__ __align__(16) __bf16 Ps[4][32][68];  // per-wave P          17408 B
  const int t = threadIdx.x;
  const int lane = t & 63, w = t >> 6;
  const int l15 = lane & 15, quad = lane >> 4;
  const int s0 = (15 - blockIdx.x) * 128;  // heavy tiles first
  const int h = blockIdx.y, b = blockIdx.z;
  const int kvh = h >> 2;  // G=4

  // Q fragments: aQ[mi][kt], A-layout m=lane&15, k=quad*8+j
  bf16x8 aQ[2][4];
#pragma unroll
  for (int mi = 0; mi < 2; ++mi) {
    const int qrow = s0 + w * 32 + mi * 16 + l15;
    const __bf16* qp = qio + ((long)((b * S_ + qrow) * H_ + h)) * HD_ + quad * 8;
#pragma unroll
    for (int kt = 0; kt < 4; ++kt) aQ[mi][kt] = *(const bf16x8*)(qp + kt * 32);
  }

  // staging geometry (per thread, 4 chunks of 16B each for K and V)
  const int krow = t >> 4;                  // K: base row 0..15 (+it*16)
  const int kcol8 = (t & 15) * 8;           // K: elem offset in row
  const int kswz = ((t & 15) * 16) ^ ((krow & 7) << 4);
  const int vrow = t >> 3;                  // V: base row (hd) 0..31 (+it*32)
  const int vcol8 = (t & 7) * 8;
  const int vswz = ((t & 7) * 16) ^ ((vrow & 7) << 4);
  const __bf16* kc_h = kc + (long)(b * KV_ + kvh) * T_ * HD_;
  const __bf16* vt_h = vt + (long)((b * KV_ + kvh) * HD_) * T_;
  char* KsW = (char*)Ks;
  char* VsW = (char*)Vs;

  f32x4 O[2][8];
#pragma unroll
  for (int mi = 0; mi < 2; ++mi)
#pragma unroll
    for (int f = 0; f < 8; ++f)
#pragma unroll
      for (int e = 0; e < 4; ++e) O[mi][f][e] = 0.0f;
  float m_r[2][4], l_r[2][4];
#pragma unroll
  for (int mi = 0; mi < 2; ++mi)
#pragma unroll
    for (int r = 0; r < 4; ++r) { m_r[mi][r] = -__builtin_inff(); l_r[mi][r] = 0.0f; }

  bf16x8 ones;
#pragma unroll
  for (int e = 0; e < 8; ++e) ones[e] = (__bf16)1.0f;

  const float C2 = 1.4426950408889634f * 0.08838834764831845f;  // log2e/sqrt(128)
  const int ntiles = (P_ + s0 + 128) / 64;
  const int wave_last_key = P_ + s0 + w * 32 + 31;   // max key this wave needs
  const int wave_min_bound = P_ + s0 + w * 32;       // min bound over wave rows

  const int sw = (l15 & 7) << 4;  // read-side swizzle (row&7 == l15&7 for K,V)
  const char* KsB = (const char*)Ks;
  const char* VsB = (const char*)Vs;

  for (int tile = 0; tile < ntiles; ++tile) {
    const int j0 = tile * 64;
    __syncthreads();  // prior tile's LDS reads done
    {
      // load this tile (8 outstanding 16B loads), then land into swizzled LDS
      bf16x8 kreg[4], vreg[4];
#pragma unroll
      for (int it = 0; it < 4; ++it) {
        kreg[it] = *(const bf16x8*)(kc_h + (long)(j0 + it * 16 + krow) * HD_ + kcol8);
        vreg[it] = *(const bf16x8*)(vt_h + (long)(it * 32 + vrow) * T_ + j0 + vcol8);
      }
#pragma unroll
      for (int it = 0; it < 4; ++it) {
        *(bf16x8*)(KsW + (it * 16 + krow) * 256 + kswz) = kreg[it];
        *(bf16x8*)(VsW + (it * 32 + vrow) * 128 + vswz) = vreg[it];
      }
    }
    __syncthreads();  // K/V tile ready

    if (j0 > wave_last_key) continue;  // trailing tile not needed by this wave

    // QK^T: sc[mi][kf] = scores [32 q][64 keys]
    f32x4 sc[2][4];
#pragma unroll
    for (int mi = 0; mi < 2; ++mi)
#pragma unroll
      for (int kf = 0; kf < 4; ++kf)
#pragma unroll
        for (int e = 0; e < 4; ++e) sc[mi][kf][e] = 0.0f;
#pragma unroll
    for (int kf = 0; kf < 4; ++kf) {
#pragma unroll
      for (int kt = 0; kt < 4; ++kt) {
        bf16x8 bk = *(const bf16x8*)(
            KsB + ((((kf * 16 + l15) << 8) + kt * 64 + quad * 16) ^ sw));
        sc[0][kf] = __builtin_amdgcn_mfma_f32_16x16x32_bf16(aQ[0][kt], bk, sc[0][kf], 0, 0, 0);
        sc[1][kf] = __builtin_amdgcn_mfma_f32_16x16x32_bf16(aQ[1][kt], bk, sc[1][kf], 0, 0, 0);
      }
    }

    // online softmax (C layout: key=kf*16+(lane&15), q-row=quad*4+r)
    const bool need_mask = (j0 + 63 > wave_min_bound);  // wave-uniform branch
    float alpha[2][4];
#pragma unroll
    for (int mi = 0; mi < 2; ++mi) {
#pragma unroll
      for (int r = 0; r < 4; ++r) {
        float v0 = sc[mi][0][r], v1 = sc[mi][1][r];
        float v2 = sc[mi][2][r], v3 = sc[mi][3][r];
        if (need_mask) {
          const int bound = P_ + s0 + w * 32 + mi * 16 + quad * 4 + r;
          v0 = (j0 + l15 <= bound) ? v0 : -__builtin_inff();
          v1 = (j0 + 16 + l15 <= bound) ? v1 : -__builtin_inff();
          v2 = (j0 + 32 + l15 <= bound) ? v2 : -__builtin_inff();
          v3 = (j0 + 48 + l15 <= bound) ? v3 : -__builtin_inff();
        }
        float mt = fmaxf(fmaxf(v0, v1), fmaxf(v2, v3));
        mt = fmaxf(mt, __shfl_xor(mt, 1));
        mt = fmaxf(mt, __shfl_xor(mt, 2));
        mt = fmaxf(mt, __shfl_xor(mt, 4));
        mt = fmaxf(mt, __shfl_xor(mt, 8));
        const float mn = fmaxf(m_r[mi][r], mt);
        const float p0 = exp2f((v0 - mn) * C2);
        const float p1 = exp2f((v1 - mn) * C2);
        const float p2 = exp2f((v2 - mn) * C2);
        const float p3 = exp2f((v3 - mn) * C2);
        alpha[mi][r] = exp2f((m_r[mi][r] - mn) * C2);
        m_r[mi][r] = mn;
        const int row = mi * 16 + quad * 4 + r;
        Ps[w][row][l15] = (__bf16)p0;
        Ps[w][row][16 + l15] = (__bf16)p1;
        Ps[w][row][32 + l15] = (__bf16)p2;
        Ps[w][row][48 + l15] = (__bf16)p3;
      }
    }
    // rescale O
#pragma unroll
    for (int mi = 0; mi < 2; ++mi)
#pragma unroll
      for (int f = 0; f < 8; ++f)
#pragma unroll
        for (int r = 0; r < 4; ++r) O[mi][f][r] *= alpha[mi][r];

    // PV + row sums via MFMA (each bV feeds 2 MFMAs)
    f32x4 sums[2];
#pragma unroll
    for (int e = 0; e < 4; ++e) { sums[0][e] = 0.0f; sums[1][e] = 0.0f; }
#pragma unroll
    for (int kf2 = 0; kf2 < 2; ++kf2) {
      bf16x8 aP0 = *(const bf16x8*)(&Ps[w][l15][kf2 * 32 + quad * 8]);
      bf16x8 aP1 = *(const bf16x8*)(&Ps[w][16 + l15][kf2 * 32 + quad * 8]);
      sums[0] = __builtin_amdgcn_mfma_f32_16x16x32_bf16(aP0, ones, sums[0], 0, 0, 0);
      sums[1] = __builtin_amdgcn_mfma_f32_16x16x32_bf16(aP1, ones, sums[1], 0, 0, 0);
#pragma unroll
      for (int f = 0; f < 8; ++f) {
        bf16x8 bV = *(const bf16x8*)(
            VsB + ((((f * 16 + l15) << 7) + kf2 * 64 + quad * 16) ^ sw));
        O[0][f] = __builtin_amdgcn_mfma_f32_16x16x32_bf16(aP0, bV, O[0][f], 0, 0, 0);
        O[1][f] = __builtin_amdgcn_mfma_f32_16x16x32_bf16(aP1, bV, O[1][f], 0, 0, 0);
      }
    }
#pragma unroll
    for (int mi = 0; mi < 2; ++mi)
#pragma unroll
      for (int r = 0; r < 4; ++r)
        l_r[mi][r] = l_r[mi][r] * alpha[mi][r] + sums[mi][r];
  }

  // epilogue: normalize, store in-place
#pragma unroll
  for (int mi = 0; mi < 2; ++mi) {
#pragma unroll
    for (int r = 0; r < 4; ++r) {
      const float inv = 1.0f / l_r[mi][r];
      const long row =
          (long)((b * S_ + s0 + w * 32 + mi * 16 + quad * 4 + r) * H_ + h);
#pragma unroll
      for (int f = 0; f < 8; ++f)
        qio[row * HD_ + f * 16 + l15] = (__bf16)(O[mi][f][r] * inv);
    }
  }
}

extern "C" void kernel_launch(void* const* d_in, const int* in_sizes, int n_in,
                              void* d_out, int out_size, void* d_ws, size_t ws_size,
                              hipStream_t stream) {
  const float* x  = (const float*)d_in[0];
  const float* pk = (const float*)d_in[1];
  const float* pv = (const float*)d_in[2];
  const float* Wq = (const float*)d_in[3];
  const float* Wk = (const float*)d_in[4];
  const float* Wv = (const float*)d_in[5];
  const float* Wo = (const float*)d_in[6];
  float* out = (float*)d_out;
  char* ws = (char*)d_ws;
  // workspace layout:
  __bf16* wt  = (__bf16*)ws;                        // 32M: W^T staging
  __bf16* kvb = (__bf16*)(ws + (size_t)16777216);   // 16M: fused k/v gemm out
  __bf16* q   = (__bf16*)(ws + (size_t)33554432);   // 32M: [B,S,H,HD]
  __bf16* xb  = (__bf16*)(ws + (size_t)67108864);   // 32M: x bf16 (dead after kv gemm)
  __bf16* kc  = (__bf16*)(ws + (size_t)67108864);   // 12.6M (aliases dead xb)
  __bf16* vt  = (__bf16*)(ws + (size_t)79691776);   // 12.6M

  dim3 tb(32, 8);
  cvt_f32_bf16<<<8192, 256, 0, stream>>>(x, xb);
  // q = x @ Wq
  transpose2d<<<dim3(128, 128), tb, 0, stream>>>(Wq, wt, D_, D_);
  gemm_bt<__bf16><<<dim3(32, 32), 256, 0, stream>>>(xb, wt, q, B_ * S_, D_, D_);
  // fused [k|v] = x @ [Wk|Wv]  (N=2048, 512 blocks)
  transpose2d<<<dim3(32, 128), tb, 0, stream>>>(Wk, wt, D_, KV_ * HD_);
  transpose2d<<<dim3(32, 128), tb, 0, stream>>>(Wv, wt + (size_t)1024 * 4096, D_, KV_ * HD_);
  gemm_bt<__bf16><<<dim3(16, 32), 256, 0, stream>>>(xb, wt, kvb, B_ * S_, 2048, D_);
  // concat bf16 caches (xb dead from here; kc/vt overlay it)
  build_kc<<<3072, 256, 0, stream>>>(pk, kvb, kc);
  build_vt<<<dim3(96, 4, 16), tb, 0, stream>>>(pv, kvb, vt);
  // attention (in-place on q); heavy s-tiles dispatch first via reversed x
  attn_kernel<<<dim3(16, 32, 2), 256, 0, stream>>>(q, kc, vt);
  // out = attn @ Wo  (f32 output)
  transpose2d<<<dim3(128, 128), tb, 0, stream>>>(Wo, wt, D_, D_);
  gemm_bt<float><<<dim3(32, 32), 256, 0, stream>>>(q, wt, out, B_ * S_, D_, D_);
}

// Round 5
// 1049.955 us; speedup vs baseline: 1.9770x; 1.0203x over previous
//
#include <hip/hip_runtime.h>

typedef __bf16 bf16x8 __attribute__((ext_vector_type(8)));
typedef float f32x4 __attribute__((ext_vector_type(4)));
using gptr_t = const __attribute__((address_space(1))) void*;
using sptr_t = __attribute__((address_space(3))) void*;

#define B_ 2
#define S_ 2048
#define D_ 4096
#define H_ 32
#define KV_ 8
#define G_ 4
#define HD_ 128
#define P_ 1024
#define T_ 3072

__device__ inline bf16x8 cvt8(const float4 a, const float4 b) {
  bf16x8 r;
  r[0] = (__bf16)a.x; r[1] = (__bf16)a.y; r[2] = (__bf16)a.z; r[3] = (__bf16)a.w;
  r[4] = (__bf16)b.x; r[5] = (__bf16)b.y; r[6] = (__bf16)b.z; r[7] = (__bf16)b.w;
  return r;
}

// ---------------- f32 -> bf16 elementwise convert (8 elems/thread) ----------
__global__ __launch_bounds__(256) void cvt_f32_bf16(const float* __restrict__ in,
                                                    __bf16* __restrict__ out) {
  const long i = ((long)blockIdx.x * 256 + threadIdx.x) * 8;
  float4 a = *(const float4*)(in + i);
  float4 b = *(const float4*)(in + i + 4);
  *(bf16x8*)(out + i) = cvt8(a, b);
}

// ------------- transpose: out[c][r] = bf16(in[r][c]), in f32 R x C ----------
__global__ __launch_bounds__(256) void transpose2d(const float* __restrict__ in,
                                                   __bf16* __restrict__ out,
                                                   int R, int C) {
  __shared__ float tl[32][33];
  const int tx = threadIdx.x, ty = threadIdx.y;
  const int c0 = blockIdx.x * 32, r0 = blockIdx.y * 32;
#pragma unroll
  for (int i = 0; i < 4; ++i)
    tl[ty + i * 8][tx] = in[(long)(r0 + ty + i * 8) * C + c0 + tx];
  __syncthreads();
#pragma unroll
  for (int i = 0; i < 4; ++i)
    out[(long)(c0 + ty + i * 8) * R + r0 + tx] = (__bf16)tl[tx][ty + i * 8];
}

// ------- build concat bf16 K cache: kc[b][kvh][j][hd], j in [0,T) -----------
__global__ __launch_bounds__(256) void build_kc(const float* __restrict__ pk,
                                                const __bf16* __restrict__ kv,
                                                __bf16* __restrict__ kc) {
  const int i = blockIdx.x * 256 + threadIdx.x;
  const int hd0 = (i & 15) * 8;
  const int row = i >> 4;                 // (b*KV+kvh)*T + j
  const int j = row % T_;
  const int bk = row / T_;
  const int b = bk >> 3, kvh = bk & 7;
  bf16x8 v;
  if (j < P_) {
    const float* src = pk + ((long)((b * P_ + j) * KV_ + kvh)) * HD_ + hd0;
    v = cvt8(*(const float4*)src, *(const float4*)(src + 4));
  } else {
    v = *(const bf16x8*)(kv + (long)(b * S_ + (j - P_)) * 2048 + kvh * HD_ + hd0);
  }
  *(bf16x8*)(kc + (long)row * HD_ + hd0) = v;
}

// ------- build transposed+concatenated V: vt[b][kvh][hd][j], j in [0,T) -----
__global__ __launch_bounds__(256) void build_vt(const float* __restrict__ past_v,
                                                const __bf16* __restrict__ kv,
                                                __bf16* __restrict__ vt) {
  __shared__ float tl[32][33];
  const int tx = threadIdx.x, ty = threadIdx.y;
  const int j0 = blockIdx.x * 32, hd0 = blockIdx.y * 32;
  const int b = blockIdx.z >> 3, kvh = blockIdx.z & 7;
#pragma unroll
  for (int i = 0; i < 4; ++i) {
    const int j = j0 + ty + i * 8;
    float val = (j < P_)
        ? past_v[((long)((b * P_ + j) * KV_ + kvh)) * HD_ + hd0 + tx]
        : (float)kv[(long)(b * S_ + (j - P_)) * 2048 + 1024 + kvh * HD_ + hd0 + tx];
    tl[ty + i * 8][tx] = val;
  }
  __syncthreads();
#pragma unroll
  for (int i = 0; i < 4; ++i)
    vt[((long)((b * KV_ + kvh) * HD_ + hd0 + ty + i * 8)) * T_ + j0 + tx] =
        (__bf16)tl[tx][ty + i * 8];
}

// ---------------- GEMM (m97 structure): C[M,N] = A[M,K] @ Bt[N,K]^T ---------
template <typename OutT>
__global__ __launch_bounds__(256, 3) void gemm_bt(const __bf16* __restrict__ A,
                                                  const __bf16* __restrict__ Bt,
                                                  OutT* __restrict__ C,
                                                  int M, int N, int K) {
  __shared__ __align__(16) __bf16 As[128][32];
  __shared__ __align__(16) __bf16 Bs[128][32];
  const int t = threadIdx.x;
  const int lane = t & 63, wave = t >> 6;
  const int wm = (wave >> 1) * 64, wn = (wave & 1) * 64;
  const int l15 = lane & 15, quad = lane >> 4;
  const long m0 = (long)blockIdx.y * 128, n0 = (long)blockIdx.x * 128;

  const int srow = wave * 32 + (lane >> 2);
  const int scol = (lane & 3) * 8;
  const __bf16* Ap = A + (m0 + srow) * K + scol;
  const __bf16* Bp = Bt + (n0 + srow) * K + scol;
  const long rstep = 16L * K;
  sptr_t ldsA0 = (sptr_t)&As[wave * 32][0];
  sptr_t ldsA1 = (sptr_t)&As[wave * 32 + 16][0];
  sptr_t ldsB0 = (sptr_t)&Bs[wave * 32][0];
  sptr_t ldsB1 = (sptr_t)&Bs[wave * 32 + 16][0];

  f32x4 acc[4][4];
#pragma unroll
  for (int i = 0; i < 4; ++i)
#pragma unroll
    for (int j = 0; j < 4; ++j)
#pragma unroll
      for (int e = 0; e < 4; ++e) acc[i][j][e] = 0.0f;

  const int nk = K >> 5;
  for (int kt = 0; kt < nk; ++kt) {
    __syncthreads();  // prior tile's frag reads done
    __builtin_amdgcn_global_load_lds((gptr_t)(Ap + kt * 32), ldsA0, 16, 0, 0);
    __builtin_amdgcn_global_load_lds((gptr_t)(Ap + rstep + kt * 32), ldsA1, 16, 0, 0);
    __builtin_amdgcn_global_load_lds((gptr_t)(Bp + kt * 32), ldsB0, 16, 0, 0);
    __builtin_amdgcn_global_load_lds((gptr_t)(Bp + rstep + kt * 32), ldsB1, 16, 0, 0);
    __syncthreads();  // vmcnt(0) drain + barrier: LDS tile ready
    bf16x8 aF[4], bF[4];
#pragma unroll
    for (int i = 0; i < 4; ++i)
      aF[i] = *(const bf16x8*)(&As[wm + i * 16 + l15][quad * 8]);
#pragma unroll
    for (int i = 0; i < 4; ++i)
      bF[i] = *(const bf16x8*)(&Bs[wn + i * 16 + l15][quad * 8]);
#pragma unroll
    for (int i = 0; i < 4; ++i)
#pragma unroll
      for (int j = 0; j < 4; ++j)
        acc[i][j] = __builtin_amdgcn_mfma_f32_16x16x32_bf16(aF[i], bF[j],
                                                            acc[i][j], 0, 0, 0);
  }

  // epilogue: C/D layout col=lane&15, row=quad*4+reg
#pragma unroll
  for (int i = 0; i < 4; ++i) {
    const long r0 = m0 + wm + i * 16 + quad * 4;
#pragma unroll
    for (int j = 0; j < 4; ++j) {
      const long col = n0 + wn + j * 16 + l15;
#pragma unroll
      for (int r = 0; r < 4; ++r)
        C[(r0 + r) * N + col] = (OutT)acc[i][j][r];
    }
  }
}

// ---------------- fused causal GQA flash attention ---------------------------
// grid (S/128, H, B), heavy s-tiles first. 256 threads; wave owns 32 q-rows.
// 64-key tiles. Double-buffered staging at __launch_bounds__(256, 2):
//   prologue: load tile-0 K/V into regs (8x16B plain cache-allocating loads).
//   loop: barrier; swizzled ds_write_b128 of staged regs; barrier;
//         issue tile t+1 loads (latency hides under tile-t compute); compute.
// This is the round-2 structure, which failed ONLY because (256,3) capped
// the unified reg budget at ~170 and spilled the 64 staging VGPRs
// (VGPR_Count 84, +940 MB scratch). At (256,2) budget=256: 112 base + 64
// staging fits. Tripwire: attn WRITE_SIZE must stay 32768 KB (no scratch).
// No global_load_lds (bypasses cache allocation; 45x-re-read KV needs
// L2/LLC: round 1 FETCH 121MB -> 1.18GB). XOR swizzle byte ^= ((row&7)<<4)
// on write and read sides. Ps stride 68.
__global__ __launch_bounds__(256, 2) void attn_kernel(
    __bf16* qio,                     // [B,S,H,HD] in: Q, out: attn out (in-place)
    const __bf16* __restrict__ kc,   // [B,KV,T,HD] bf16 concat cache
    const __bf16* __restrict__ vt) { // [B,KV,HD,T]
  __shared__ __align__(16) __bf16 Ks[64 * 128];   // swizzled [key][hd]  16384 B
  __shared__ __align__(16) __bf16 Vs[128 * 64];   // swizzled [hd][key]  16384 B
  __shared__ __align__(16) __bf16 Ps[4][32][68];  // per-wave P          17408 B
  const int t = threadIdx.x;
  const int lane = t & 63, w = t >> 6;
  const int l15 = lane & 15, quad = lane >> 4;
  const int s0 = (15 - blockIdx.x) * 128;  // heavy tiles first
  const int h = blockIdx.y, b = blockIdx.z;
  const int kvh = h >> 2;  // G=4

  // Q fragments: aQ[mi][kt], A-layout m=lane&15, k=quad*8+j
  bf16x8 aQ[2][4];
#pragma unroll
  for (int mi = 0; mi < 2; ++mi) {
    const int qrow = s0 + w * 32 + mi * 16 + l15;
    const __bf16* qp = qio + ((long)((b * S_ + qrow) * H_ + h)) * HD_ + quad * 8;
#pragma unroll
    for (int kt = 0; kt < 4; ++kt) aQ[mi][kt] = *(const bf16x8*)(qp + kt * 32);
  }

  // staging geometry (per thread, 4 chunks of 16B each for K and V)
  const int krow = t >> 4;                  // K: base row 0..15 (+it*16)
  const int kcol8 = (t & 15) * 8;           // K: elem offset in row
  const int kswz = ((t & 15) * 16) ^ ((krow & 7) << 4);
  const int vrow = t >> 3;                  // V: base row (hd) 0..31 (+it*32)
  const int vcol8 = (t & 7) * 8;
  const int vswz = ((t & 7) * 16) ^ ((vrow & 7) << 4);
  const __bf16* kc_h = kc + (long)(b * KV_ + kvh) * T_ * HD_;
  const __bf16* vt_h = vt + (long)((b * KV_ + kvh) * HD_) * T_;
  char* KsW = (char*)Ks;
  char* VsW = (char*)Vs;

  f32x4 O[2][8];
#pragma unroll
  for (int mi = 0; mi < 2; ++mi)
#pragma unroll
    for (int f = 0; f < 8; ++f)
#pragma unroll
      for (int e = 0; e < 4; ++e) O[mi][f][e] = 0.0f;
  float m_r[2][4], l_r[2][4];
#pragma unroll
  for (int mi = 0; mi < 2; ++mi)
#pragma unroll
    for (int r = 0; r < 4; ++r) { m_r[mi][r] = -__builtin_inff(); l_r[mi][r] = 0.0f; }

  bf16x8 ones;
#pragma unroll
  for (int e = 0; e < 8; ++e) ones[e] = (__bf16)1.0f;

  const float C2 = 1.4426950408889634f * 0.08838834764831845f;  // log2e/sqrt(128)
  const int ntiles = (P_ + s0 + 128) / 64;
  const int wave_last_key = P_ + s0 + w * 32 + 31;   // max key this wave needs
  const int wave_min_bound = P_ + s0 + w * 32;       // min bound over wave rows

  const int sw = (l15 & 7) << 4;  // read-side swizzle (row&7 == l15&7 for K,V)
  const char* KsB = (const char*)Ks;
  const char* VsB = (const char*)Vs;

  // prologue: issue loads for tile 0
  bf16x8 kreg[4], vreg[4];
#pragma unroll
  for (int it = 0; it < 4; ++it) {
    kreg[it] = *(const bf16x8*)(kc_h + (long)(it * 16 + krow) * HD_ + kcol8);
    vreg[it] = *(const bf16x8*)(vt_h + (long)(it * 32 + vrow) * T_ + vcol8);
  }

  for (int tile = 0; tile < ntiles; ++tile) {
    const int j0 = tile * 64;
    __syncthreads();  // prior tile's LDS reads done
    // land staged regs into swizzled LDS
#pragma unroll
    for (int it = 0; it < 4; ++it) {
      *(bf16x8*)(KsW + (it * 16 + krow) * 256 + kswz) = kreg[it];
      *(bf16x8*)(VsW + (it * 32 + vrow) * 128 + vswz) = vreg[it];
    }
    __syncthreads();  // K/V tile ready

    // issue loads for next tile (in flight under this tile's compute)
    const int jn = (tile + 1 < ntiles) ? (tile + 1) * 64 : 0;
#pragma unroll
    for (int it = 0; it < 4; ++it) {
      kreg[it] = *(const bf16x8*)(kc_h + (long)(jn + it * 16 + krow) * HD_ + kcol8);
      vreg[it] = *(const bf16x8*)(vt_h + (long)(it * 32 + vrow) * T_ + jn + vcol8);
    }

    if (j0 > wave_last_key) continue;  // trailing tile not needed by this wave

    // QK^T: sc[mi][kf] = scores [32 q][64 keys]
    f32x4 sc[2][4];
#pragma unroll
    for (int mi = 0; mi < 2; ++mi)
#pragma unroll
      for (int kf = 0; kf < 4; ++kf)
#pragma unroll
        for (int e = 0; e < 4; ++e) sc[mi][kf][e] = 0.0f;
#pragma unroll
    for (int kf = 0; kf < 4; ++kf) {
#pragma unroll
      for (int kt = 0; kt < 4; ++kt) {
        bf16x8 bk = *(const bf16x8*)(
            KsB + ((((kf * 16 + l15) << 8) + kt * 64 + quad * 16) ^ sw));
        sc[0][kf] = __builtin_amdgcn_mfma_f32_16x16x32_bf16(aQ[0][kt], bk, sc[0][kf], 0, 0, 0);
        sc[1][kf] = __builtin_amdgcn_mfma_f32_16x16x32_bf16(aQ[1][kt], bk, sc[1][kf], 0, 0, 0);
      }
    }

    // online softmax (C layout: key=kf*16+(lane&15), q-row=quad*4+r)
    const bool need_mask = (j0 + 63 > wave_min_bound);  // wave-uniform branch
    float alpha[2][4];
#pragma unroll
    for (int mi = 0; mi < 2; ++mi) {
#pragma unroll
      for (int r = 0; r < 4; ++r) {
        float v0 = sc[mi][0][r], v1 = sc[mi][1][r];
        float v2 = sc[mi][2][r], v3 = sc[mi][3][r];
        if (need_mask) {
          const int bound = P_ + s0 + w * 32 + mi * 16 + quad * 4 + r;
          v0 = (j0 + l15 <= bound) ? v0 : -__builtin_inff();
          v1 = (j0 + 16 + l15 <= bound) ? v1 : -__builtin_inff();
          v2 = (j0 + 32 + l15 <= bound) ? v2 : -__builtin_inff();
          v3 = (j0 + 48 + l15 <= bound) ? v3 : -__builtin_inff();
        }
        float mt = fmaxf(fmaxf(v0, v1), fmaxf(v2, v3));
        mt = fmaxf(mt, __shfl_xor(mt, 1));
        mt = fmaxf(mt, __shfl_xor(mt, 2));
        mt = fmaxf(mt, __shfl_xor(mt, 4));
        mt = fmaxf(mt, __shfl_xor(mt, 8));
        const float mn = fmaxf(m_r[mi][r], mt);
        const float p0 = exp2f((v0 - mn) * C2);
        const float p1 = exp2f((v1 - mn) * C2);
        const float p2 = exp2f((v2 - mn) * C2);
        const float p3 = exp2f((v3 - mn) * C2);
        alpha[mi][r] = exp2f((m_r[mi][r] - mn) * C2);
        m_r[mi][r] = mn;
        const int row = mi * 16 + quad * 4 + r;
        Ps[w][row][l15] = (__bf16)p0;
        Ps[w][row][16 + l15] = (__bf16)p1;
        Ps[w][row][32 + l15] = (__bf16)p2;
        Ps[w][row][48 + l15] = (__bf16)p3;
      }
    }
    // rescale O
#pragma unroll
    for (int mi = 0; mi < 2; ++mi)
#pragma unroll
      for (int f = 0; f < 8; ++f)
#pragma unroll
        for (int r = 0; r < 4; ++r) O[mi][f][r] *= alpha[mi][r];

    // PV + row sums via MFMA (each bV feeds 2 MFMAs)
    f32x4 sums[2];
#pragma unroll
    for (int e = 0; e < 4; ++e) { sums[0][e] = 0.0f; sums[1][e] = 0.0f; }
#pragma unroll
    for (int kf2 = 0; kf2 < 2; ++kf2) {
      bf16x8 aP0 = *(const bf16x8*)(&Ps[w][l15][kf2 * 32 + quad * 8]);
      bf16x8 aP1 = *(const bf16x8*)(&Ps[w][16 + l15][kf2 * 32 + quad * 8]);
      sums[0] = __builtin_amdgcn_mfma_f32_16x16x32_bf16(aP0, ones, sums[0], 0, 0, 0);
      sums[1] = __builtin_amdgcn_mfma_f32_16x16x32_bf16(aP1, ones, sums[1], 0, 0, 0);
#pragma unroll
      for (int f = 0; f < 8; ++f) {
        bf16x8 bV = *(const bf16x8*)(
            VsB + ((((f * 16 + l15) << 7) + kf2 * 64 + quad * 16) ^ sw));
        O[0][f] = __builtin_amdgcn_mfma_f32_16x16x32_bf16(aP0, bV, O[0][f], 0, 0, 0);
        O[1][f] = __builtin_amdgcn_mfma_f32_16x16x32_bf16(aP1, bV, O[1][f], 0, 0, 0);
      }
    }
#pragma unroll
    for (int mi = 0; mi < 2; ++mi)
#pragma unroll
      for (int r = 0; r < 4; ++r)
        l_r[mi][r] = l_r[mi][r] * alpha[mi][r] + sums[mi][r];
  }

  // epilogue: normalize, store in-place
#pragma unroll
  for (int mi = 0; mi < 2; ++mi) {
#pragma unroll
    for (int r = 0; r < 4; ++r) {
      const float inv = 1.0f / l_r[mi][r];
      const long row =
          (long)((b * S_ + s0 + w * 32 + mi * 16 + quad * 4 + r) * H_ + h);
#pragma unroll
      for (int f = 0; f < 8; ++f)
        qio[row * HD_ + f * 16 + l15] = (__bf16)(O[mi][f][r] * inv);
    }
  }
}

extern "C" void kernel_launch(void* const* d_in, const int* in_sizes, int n_in,
                              void* d_out, int out_size, void* d_ws, size_t ws_size,
                              hipStream_t stream) {
  const float* x  = (const float*)d_in[0];
  const float* pk = (const float*)d_in[1];
  const float* pv = (const float*)d_in[2];
  const float* Wq = (const float*)d_in[3];
  const float* Wk = (const float*)d_in[4];
  const float* Wv = (const float*)d_in[5];
  const float* Wo = (const float*)d_in[6];
  float* out = (float*)d_out;
  char* ws = (char*)d_ws;
  // workspace layout:
  __bf16* wt  = (__bf16*)ws;                        // 32M: W^T staging
  __bf16* kvb = (__bf16*)(ws + (size_t)16777216);   // 16M: fused k/v gemm out
  __bf16* q   = (__bf16*)(ws + (size_t)33554432);   // 32M: [B,S,H,HD]
  __bf16* xb  = (__bf16*)(ws + (size_t)67108864);   // 32M: x bf16 (dead after kv gemm)
  __bf16* kc  = (__bf16*)(ws + (size_t)67108864);   // 12.6M (aliases dead xb)
  __bf16* vt  = (__bf16*)(ws + (size_t)79691776);   // 12.6M

  dim3 tb(32, 8);
  cvt_f32_bf16<<<8192, 256, 0, stream>>>(x, xb);
  // q = x @ Wq
  transpose2d<<<dim3(128, 128), tb, 0, stream>>>(Wq, wt, D_, D_);
  gemm_bt<__bf16><<<dim3(32, 32), 256, 0, stream>>>(xb, wt, q, B_ * S_, D_, D_);
  // fused [k|v] = x @ [Wk|Wv]  (N=2048, 512 blocks)
  transpose2d<<<dim3(32, 128), tb, 0, stream>>>(Wk, wt, D_, KV_ * HD_);
  transpose2d<<<dim3(32, 128), tb, 0, stream>>>(Wv, wt + (size_t)1024 * 4096, D_, KV_ * HD_);
  gemm_bt<__bf16><<<dim3(16, 32), 256, 0, stream>>>(xb, wt, kvb, B_ * S_, 2048, D_);
  // concat bf16 caches (xb dead from here; kc/vt overlay it)
  build_kc<<<3072, 256, 0, stream>>>(pk, kvb, kc);
  build_vt<<<dim3(96, 4, 16), tb, 0, stream>>>(pv, kvb, vt);
  // attention (in-place on q); heavy s-tiles dispatch first via reversed x
  attn_kernel<<<dim3(16, 32, 2), 256, 0, stream>>>(q, kc, vt);
  // out = attn @ Wo  (f32 output)
  transpose2d<<<dim3(128, 128), tb, 0, stream>>>(Wo, wt, D_, D_);
  gemm_bt<float><<<dim3(32, 32), 256, 0, stream>>>(q, wt, out, B_ * S_, D_, D_);
}